// Round 1
// baseline (398.696 us; speedup 1.0000x reference)
//
#include <hip/hip_runtime.h>
#include <cstddef>

#define H 128
#define W 128
#define TILE_R 32
#define LROWS (TILE_R + 2)   // 34
#define P_THRESH 20

// mask value: 0..7 = direction if prob<=20, 8 = inactive
__global__ __launch_bounds__(256, 4)
void brown_kernel(const float* __restrict__ inp,
                  const int*  __restrict__ dirp,
                  const int*  __restrict__ prb,
                  float* __restrict__ out)
{
    __shared__ float s_in[LROWS * W];
    __shared__ int   s_mk[LROWS * W];

    const int tid   = threadIdx.x;
    const int bid   = blockIdx.x;
    const int slice = bid >> 2;              // 4 row-tiles per slice
    const int r0    = (bid & 3) * TILE_R;
    const size_t base = (size_t)slice * (size_t)(H * W);

    // ---- Stage 34 rows of input + fused mask into LDS ----
    // halo rows outside the slice: input gets the REFLECT row (correct for avg),
    // mask gets 8 (no A-writes can originate out of range).
    for (int idx = tid; idx < LROWS * (W / 4); idx += 256) {
        const int L  = idx >> 5;       // /(W/4)=32
        const int c4 = idx & 31;
        const int gr = r0 - 1 + L;
        const int gri = (gr < 0) ? 1 : ((gr >= H) ? (H - 2) : gr);
        const float4 iv = ((const float4*)(inp + base + (size_t)gri * W))[c4];
        ((float4*)(s_in + L * W))[c4] = iv;
        int4 mv;
        if (gr >= 0 && gr < H) {
            const int4 dv = ((const int4*)(dirp + base + (size_t)gr * W))[c4];
            const int4 pv = ((const int4*)(prb  + base + (size_t)gr * W))[c4];
            mv.x = (pv.x <= P_THRESH) ? dv.x : 8;
            mv.y = (pv.y <= P_THRESH) ? dv.y : 8;
            mv.z = (pv.z <= P_THRESH) ? dv.z : 8;
            mv.w = (pv.w <= P_THRESH) ? dv.w : 8;
        } else {
            mv = make_int4(8, 8, 8, 8);
        }
        ((int4*)(s_mk + L * W))[c4] = mv;
    }
    __syncthreads();

    // ---- Compute: 4 pixels (one float4) per item, 4 items per thread ----
    for (int k = 0; k < 4; ++k) {
        const int item = k * 256 + tid;      // 0..1023
        const int lr = item >> 5;            // tile row 0..31
        const int cq = item & 31;            // col quad 0..31
        const int j0 = cq << 2;
        const int gi = r0 + lr;              // global row

        // 3x6 window (rows gi-1..gi+1, cols j0-1..j0+4) of values + masks.
        // Window col w <-> absolute col j0 + (w-1).
        float v[3][6];
        int   m[3][6];
        #pragma unroll
        for (int r = 0; r < 3; ++r) {
            const int Lr = lr + r;           // LDS row == global row gi-1+r
            const float4 c  = ((const float4*)(s_in + Lr * W))[cq];
            const int4   mc = ((const int4*)(s_mk + Lr * W))[cq];
            v[r][1] = c.x;  v[r][2] = c.y;  v[r][3] = c.z;  v[r][4] = c.w;
            m[r][1] = mc.x; m[r][2] = mc.y; m[r][3] = mc.z; m[r][4] = mc.w;
            const float lf = s_in[Lr * W + j0 - 1];   // garbage if cq==0, selected away
            const int   ml = s_mk[Lr * W + j0 - 1];
            const float rt = s_in[Lr * W + j0 + 4];   // garbage if cq==31, selected away
            const int   mr = s_mk[Lr * W + j0 + 4];
            v[r][0] = (cq > 0)  ? lf : c.y;   // reflect: col -1 -> col 1
            m[r][0] = (cq > 0)  ? ml : 8;     // col -1 never sources an A-write
            v[r][5] = (cq < 31) ? rt : c.z;   // reflect: col 128 -> col 126
            m[r][5] = (cq < 31) ? mr : 8;
        }

        // separable 3x3 sums
        float cs[6];
        #pragma unroll
        for (int w = 0; w < 6; ++w) cs[w] = v[0][w] + v[1][w] + v[2][w];

        float4 res;
        float* rp = (float*)&res;
        #pragma unroll
        for (int p = 0; p < 4; ++p) {
            const float avg = (cs[p] + cs[p + 1] + cs[p + 2]) * (1.0f / 9.0f);
            float val = v[1][p + 1];  // initial: input[i][j]
            int dl = -1;              // direction of last A-write (timestamp 2*dl)

            // A-writes in ascending d. Source offset (a,b) = (-di,-dj):
            // d=0:(+1,+1) d=1:(+1,0) d=2:(+1,-1) d=3:(0,+1) d=5:(0,-1) d=6:(-1,+1) d=7:(-1,0)
            // window: row = a+1, col = p+1+b. Out-of-range sources carry mask 8.
            if (m[2][p + 2] == 0) { val = v[2][p + 2]; dl = 0; }
            if (m[2][p + 1] == 1) { val = v[2][p + 1]; dl = 1; }
            if (m[2][p]     == 2) { val = v[2][p];     dl = 2; }
            if (m[1][p + 2] == 3) { val = v[1][p + 2]; dl = 3; }
            if (m[1][p]     == 5) { val = v[1][p];     dl = 5; }
            if (m[0][p + 2] == 6) { val = v[0][p + 2]; dl = 6; }
            if (m[0][p + 1] == 7) { val = v[0][p + 1]; dl = 7; }

            // B-write: own dir d0=msel at timestamp 2*msel+1; valid if active and
            // offset target in range. Wins iff msel >= dl.
            const int msel = m[1][p + 1];
            const int gj = j0 + p;
            const int q3 = msel / 3;
            const int di = q3 - 1;
            const int dj = msel - q3 * 3 - 1;
            const int ti = gi + di;
            const int tj = gj + dj;
            const bool bok = (msel < 8) & (ti >= 0) & (ti < H) & (tj >= 0) & (tj < W);
            if (bok & (msel >= dl)) val = avg;
            rp[p] = val;
        }
        ((float4*)(out + base + (size_t)gi * W))[cq] = res;
    }
}

extern "C" void kernel_launch(void* const* d_in, const int* in_sizes, int n_in,
                              void* d_out, int out_size, void* d_ws, size_t ws_size,
                              hipStream_t stream) {
    const float* inp  = (const float*)d_in[0];
    const int*   dirp = (const int*)d_in[1];
    const int*   prb  = (const int*)d_in[2];
    float* out = (float*)d_out;

    const int slices = in_sizes[0] / (H * W);          // 32*64 = 2048
    const int grid = slices * (H / TILE_R);            // 8192 blocks
    brown_kernel<<<grid, 256, 0, stream>>>(inp, dirp, prb, out);
}

// Round 2
// 388.034 us; speedup vs baseline: 1.0275x; 1.0275x over previous
//
#include <hip/hip_runtime.h>
#include <cstddef>

#define H 128
#define W 128
#define TILE_R 32
#define LROWS (TILE_R + 2)   // 34
#define P_THRESH 20

typedef __attribute__((address_space(1))) const unsigned int glo_u32;
typedef __attribute__((address_space(3))) unsigned int lds_u32;

// mask byte: 0..7 = direction if prob<=20, 8 = inactive
__global__ __launch_bounds__(256, 6)
void brown_kernel(const float* __restrict__ inp,
                  const int*  __restrict__ dirp,
                  const int*  __restrict__ prb,
                  float* __restrict__ out)
{
    __shared__ float        s_in[LROWS * W];   // 17408 B
    __shared__ unsigned int s_mk[LROWS * 32];  //  4352 B, byte-packed masks

    const int tid   = threadIdx.x;
    const int bid   = blockIdx.x;
    const int slice = bid >> 2;              // 4 row-tiles per slice
    const int r0    = (bid & 3) * TILE_R;
    const size_t base = (size_t)slice * (size_t)(H * W);

    // ---- Stage 34 rows: input via async global->LDS DMA, mask byte-packed ----
    // 1088 float4s = 17 exact wave-iterations -> wave-uniform branch; LDS dst
    // for global_load_lds is contiguous (addr = idx*16 = wave_base + lane*16).
    #pragma unroll
    for (int i = 0; i < 5; ++i) {
        const int idx = i * 256 + tid;
        if (idx < LROWS * 32) {
            const int L  = idx >> 5;
            const int c4 = idx & 31;
            const int gr = r0 - 1 + L;
            const int gri = (gr < 0) ? 1 : ((gr >= H) ? (H - 2) : gr); // reflect row for avg
            const float* gp = inp + base + (size_t)gri * W + c4 * 4;
            __builtin_amdgcn_global_load_lds((glo_u32*)gp, (lds_u32*)(s_in + idx * 4), 16, 0, 0);
            unsigned m;
            if (gr >= 0 && gr < H) {
                const int4 dv = ((const int4*)(dirp + base + (size_t)gr * W))[c4];
                const int4 pv = ((const int4*)(prb  + base + (size_t)gr * W))[c4];
                const unsigned a = (pv.x <= P_THRESH) ? (unsigned)dv.x : 8u;
                const unsigned b = (pv.y <= P_THRESH) ? (unsigned)dv.y : 8u;
                const unsigned c = (pv.z <= P_THRESH) ? (unsigned)dv.z : 8u;
                const unsigned d = (pv.w <= P_THRESH) ? (unsigned)dv.w : 8u;
                m = a | (b << 8) | (c << 16) | (d << 24);
            } else {
                m = 0x08080808u;  // out-of-image rows never source writes
            }
            s_mk[idx] = m;
        }
    }
    __syncthreads();

    // ---- Compute: each thread does 4 CONSECUTIVE rows x 4 cols (sliding window) ----
    const int cq  = tid & 31;        // col quad (cols j0..j0+3)
    const int rg  = tid >> 5;        // row group 0..7
    const int j0  = cq << 2;
    const int lrb = rg << 2;         // LDS row of window-top for rr=0
    const int cqm1 = (cq > 0)  ? cq - 1 : 0;
    const int cqp1 = (cq < 31) ? cq + 1 : 31;

    // load one window row: 6 input vals (window cols 0..5 = j0-1..j0+4) and
    // two packed mask words: ma = cols j0-1..j0+2, mb = cols j0+1..j0+4
    auto load_row = [&](int Lr, float v[6], unsigned& ma, unsigned& mb) {
        const float4 c      = ((const float4*)(s_in + Lr * W))[cq];
        const unsigned mwc  = s_mk[Lr * 32 + cq];     // stride-1: conflict-free
        const unsigned mwl  = s_mk[Lr * 32 + cqm1];
        const unsigned mwr  = s_mk[Lr * 32 + cqp1];
        const float lf = __shfl_up(c.w, 1);           // lane cq-1 col j0-1
        const float rt = __shfl_down(c.x, 1);         // lane cq+1 col j0+4
        v[1] = c.x; v[2] = c.y; v[3] = c.z; v[4] = c.w;
        v[0] = (cq > 0)  ? lf : c.y;   // reflect col -1 -> col 1
        v[5] = (cq < 31) ? rt : c.z;   // reflect col 128 -> col 126
        const unsigned ml = (cq > 0)  ? (mwl >> 24)   : 8u;
        const unsigned mr = (cq < 31) ? (mwr & 255u)  : 8u;
        ma = (mwc << 8) | ml;
        mb = (mwc >> 8) | (mr << 24);
    };

    float va[6], vb[6], vc[6];
    unsigned maa, mab, mba, mbb, mca, mcb;
    load_row(lrb + 0, va, maa, mab);
    load_row(lrb + 1, vb, mba, mbb);

    #pragma unroll
    for (int rr = 0; rr < 4; ++rr) {
        load_row(lrb + rr + 2, vc, mca, mcb);

        const int gi = r0 + lrb + rr;
        float cs[6];
        #pragma unroll
        for (int w = 0; w < 6; ++w) cs[w] = va[w] + vb[w] + vc[w];

        float4 res;
        float* rp = (float*)&res;
        #pragma unroll
        for (int p = 0; p < 4; ++p) {
            const float avg = (cs[p] + cs[p + 1] + cs[p + 2]) * (1.0f / 9.0f);
            // packed window bytes: b0 = m[win p], b1 = m[p+1], b2 = m[p+2]
            const unsigned wTop = (p < 2) ? (maa >> (8 * p)) : (mab >> (8 * (p - 2)));
            const unsigned wMid = (p < 2) ? (mba >> (8 * p)) : (mbb >> (8 * (p - 2)));
            const unsigned wBot = (p < 2) ? (mca >> (8 * p)) : (mcb >> (8 * (p - 2)));

            float val = vb[p + 1];   // input[i][j]
            int dl = -1;             // direction of last A-write
            // A-writes ascending d; source offset = (-di,-dj)
            if (((wBot >> 16) & 255u) == 0u) { val = vc[p + 2]; dl = 0; }
            if (((wBot >>  8) & 255u) == 1u) { val = vc[p + 1]; dl = 1; }
            if (( wBot        & 255u) == 2u) { val = vc[p];     dl = 2; }
            if (((wMid >> 16) & 255u) == 3u) { val = vb[p + 2]; dl = 3; }
            if (( wMid        & 255u) == 5u) { val = vb[p];     dl = 5; }
            if (((wTop >> 16) & 255u) == 6u) { val = va[p + 2]; dl = 6; }
            if (((wTop >>  8) & 255u) == 7u) { val = va[p + 1]; dl = 7; }

            // B-write (avg) at own dir msel; wins iff valid and msel >= dl
            const int msel = (int)((wMid >> 8) & 255u);  // own mask = m[1][p+1]
            const int q3 = (msel * 11) >> 5;             // msel/3 for 0..8
            const int di = q3 - 1;
            const int dj = msel - q3 * 3 - 1;
            const int ti = gi + di;
            const int tj = j0 + p + dj;
            const bool bok = (msel < 8) & ((unsigned)ti < 128u) & ((unsigned)tj < 128u);
            if (bok & (msel >= dl)) val = avg;
            rp[p] = val;
        }
        ((float4*)(out + base + (size_t)gi * W))[cq] = res;

        // rotate sliding window (register renames after full unroll)
        #pragma unroll
        for (int w = 0; w < 6; ++w) { va[w] = vb[w]; vb[w] = vc[w]; }
        maa = mba; mab = mbb; mba = mca; mbb = mcb;
    }
}

extern "C" void kernel_launch(void* const* d_in, const int* in_sizes, int n_in,
                              void* d_out, int out_size, void* d_ws, size_t ws_size,
                              hipStream_t stream) {
    const float* inp  = (const float*)d_in[0];
    const int*   dirp = (const int*)d_in[1];
    const int*   prb  = (const int*)d_in[2];
    float* out = (float*)d_out;

    const int slices = in_sizes[0] / (H * W);   // 2048
    const int grid = slices * (H / TILE_R);     // 8192
    brown_kernel<<<grid, 256, 0, stream>>>(inp, dirp, prb, out);
}